// Round 7
// baseline (3462.112 us; speedup 1.0000x reference)
//
#include <hip/hip_runtime.h>
#include <hip/hip_bf16.h>
#include <cmath>

// ============================================================================
// RAE forward, round 7: NHWC split-plane bf16x3 MFMA convs.
// Round-7 delta (vs validated round-6): fix line-utilization of the two
// non-MFMA kernels.
//   dconv4: 32-channel groups -> per-thread back-to-back 64B loads per
//           neighbor (full-line use), hi+lo -> fp32 once, same tap math.
//   conv1:  all 128 output channels per thread, 32-o groups -> 4 consecutive
//           u16x8 stores per plane (full-line writes).
// conv_mfma / prototype block unchanged.
// ============================================================================

typedef short  bf16x8 __attribute__((ext_vector_type(8)));
typedef float  f32x4  __attribute__((ext_vector_type(4)));
typedef ushort u16x8  __attribute__((ext_vector_type(8)));
typedef ushort u16x4  __attribute__((ext_vector_type(4)));

__device__ __forceinline__ ushort f2bf(float f) {
    uint u = __float_as_uint(f);
    return (ushort)((u + 0x7fffu + ((u >> 16) & 1u)) >> 16);   // RNE
}
__device__ __forceinline__ float bf2f(ushort h) {
    return __uint_as_float(((uint)h) << 16);                   // exact
}

// ---------------------------------------------------------------------------
// repack + split: wh/wl[((t*(C/8)+kcg)*O+o)*8+j] = hi/lo(W[o][8kcg+j][t])
// ---------------------------------------------------------------------------
__global__ __launch_bounds__(256)
void repack_kernel(const float* __restrict__ W, ushort* __restrict__ wh,
                   ushort* __restrict__ wl, int O, int C)
{
    int i = blockIdx.x * 256 + threadIdx.x;
    if (i >= O * C * 9) return;
    int j = i & 7;
    int rest = i >> 3;
    int o = rest % O;
    int rest2 = rest / O;
    int C8 = C >> 3;
    int kcg = rest2 % C8;
    int t = rest2 / C8;
    float v = W[(o * C + 8 * kcg + j) * 9 + t];
    ushort h = f2bf(v);
    wh[i] = h;
    wl[i] = f2bf(v - bf2f(h));
}

// ---------------------------------------------------------------------------
// conv1: x(256,3,64,64) fp32 -> y NHWC split (256,32,32,128), relu.
// grid (B, 4 site-quarters), block 256; thread = one site, all 128 o.
// ---------------------------------------------------------------------------
__global__ __launch_bounds__(256)
void conv1_kernel(const float* __restrict__ x, const float* __restrict__ W,
                  const float* __restrict__ bias, ushort* __restrict__ yh,
                  ushort* __restrict__ yl)
{
    __shared__ float xs[3 * 64 * 64];   // 48 KB
    __shared__ float ws[128 * 27];      // 13.5 KB
    __shared__ float bs[128];
    const int n = blockIdx.x, q = blockIdx.y;
    const int tid = threadIdx.x;
    const float* xp = x + (size_t)n * 3 * 64 * 64;
    for (int i = tid; i < 3 * 64 * 64 / 4; i += 256)
        ((float4*)xs)[i] = ((const float4*)xp)[i];
    for (int i = tid; i < 128 * 27; i += 256) ws[i] = W[i];
    if (tid < 128) bs[tid] = bias[tid];
    __syncthreads();

    const int pos = q * 256 + tid;        // site u*32+v
    const int u = pos >> 5, v = pos & 31;
    float xv[27];
#pragma unroll
    for (int c = 0; c < 3; c++)
#pragma unroll
        for (int kh = 0; kh < 3; kh++)
#pragma unroll
            for (int kw = 0; kw < 3; kw++) {
                int iu = 2 * u - 1 + kh, iv = 2 * v - 1 + kw;
                bool ok = (iu >= 0) & (iu < 64) & (iv >= 0) & (iv < 64);
                xv[c * 9 + kh * 3 + kw] = ok ? xs[(c << 12) + (iu << 6) + iv] : 0.f;
            }
    const size_t base = ((size_t)n * 1024 + pos) * 128;
#pragma unroll
    for (int og = 0; og < 4; og++) {
        u16x8 hv[4], lv[4];
#pragma unroll
        for (int oq = 0; oq < 4; oq++) {
#pragma unroll
            for (int oi = 0; oi < 8; oi++) {
                const int o = og * 32 + oq * 8 + oi;
                float acc = bs[o];
#pragma unroll
                for (int t = 0; t < 27; t++) acc = fmaf(xv[t], ws[o * 27 + t], acc);
                acc = fmaxf(acc, 0.f);
                ushort h = f2bf(acc);
                hv[oq][oi] = h;
                lv[oq][oi] = f2bf(acc - bf2f(h));
            }
        }
#pragma unroll
        for (int oq = 0; oq < 4; oq++) {
            *(u16x8*)&yh[base + og * 32 + 8 * oq] = hv[oq];
            *(u16x8*)&yl[base + og * 32 + 8 * oq] = lv[oq];
        }
    }
}

// ---------------------------------------------------------------------------
// MFMA implicit-GEMM conv (bf16x3, NHWC split planes). BM in {64,128}, BN=128.
// (unchanged from validated round 6)
// ---------------------------------------------------------------------------
template<bool DEC, int BM>
__global__ __launch_bounds__(256)
void conv_mfma(const ushort* __restrict__ xh, const ushort* __restrict__ xl,
               const ushort* __restrict__ awh, const ushort* __restrict__ awl,
               const float* __restrict__ bias,
               ushort* __restrict__ yh, ushort* __restrict__ yl,
               float* __restrict__ fout,
               int C, int Hi, int Wi, int O, int Ho, int Wo,
               int lgGW, int lgGHW, int act)
{
    constexpr int MFR = BM / 32;
    constexpr int ACH = BM / 64;
    __shared__ __align__(16) ushort Ash[4][BM][8];
    __shared__ __align__(16) ushort Asl[4][BM][8];
    __shared__ __align__(16) ushort Bsh[128][40];
    __shared__ __align__(16) ushort Bsl[128][40];

    const int tid = threadIdx.x;
    const int lane = tid & 63, wv = tid >> 6;
    const int wr = wv >> 1, wc = wv & 1;
    const int lr = lane & 15, lq = lane >> 4;

    const int o0 = blockIdx.y * BM;
    const int s0 = blockIdx.x * 128;

    int pi = 0, pj = 0, ntv = 0, nth = 0;
    if (DEC) {
        pi = blockIdx.z >> 1; pj = blockIdx.z & 1;
        ntv = (pi == 1) ? 1 : 2;
        nth = (pj == 1) ? 1 : 2;
    }
    const int gwm = (1 << lgGW) - 1, ghwm = (1 << lgGHW) - 1;
    const int C8 = C >> 3;

    const int kcB = tid & 3;
    const int spB = tid >> 2;          // 0..63
    int nS[2], uS[2], vS[2];
#pragma unroll
    for (int q = 0; q < 2; q++) {
        int s = s0 + spB + 64 * q;
        nS[q] = s >> lgGHW;
        int r = s & ghwm;
        uS[q] = r >> lgGW;
        vS[q] = r & gwm;
    }
    const int kcA = tid >> 6;
    const int oA = tid & 63;

    f32x4 acc[MFR][4] = {};

    const int ntaps = DEC ? ntv * nth : 9;
    for (int t = 0; t < ntaps; t++) {
        int tapidx;
        int sbase[2]; bool valid[2];
        if (!DEC) {
            int kh = t / 3, kw = t % 3;
            tapidx = t;
#pragma unroll
            for (int q = 0; q < 2; q++) {
                int iu = 2 * uS[q] - 1 + kh, iv = 2 * vS[q] - 1 + kw;
                valid[q] = (iu >= 0) & (iu < Hi) & (iv >= 0) & (iv < Wi);
                sbase[q] = ((nS[q] * Hi + iu) * Wi + iv) * C;
            }
        } else {
            int itv = t / nth, ith = t - (t / nth) * nth;
            int kh = (pi == 1) ? 1 : 2 - 2 * itv;   // da = itv
            int kw = (pj == 1) ? 1 : 2 - 2 * ith;   // db = ith
            tapidx = kh * 3 + kw;
#pragma unroll
            for (int q = 0; q < 2; q++) {
                int a = uS[q] - itv, b2 = vS[q] - ith;
                valid[q] = (a >= 0) & (b2 >= 0);
                sbase[q] = ((nS[q] * Hi + a) * Wi + b2) * C;
            }
        }
        const size_t wtap = (size_t)tapidx * C8 * O * 8;
        for (int c0 = 0; c0 < C; c0 += 32) {
            __syncthreads();   // WAR: previous step's frag reads done
            {   // stage A: pure 16B copies
                const size_t koff = wtap + (size_t)((c0 >> 3) + kcA) * O * 8;
#pragma unroll
                for (int q = 0; q < ACH; q++) {
                    const int o = oA + 64 * q;
                    const size_t aoff = koff + (size_t)(o0 + o) * 8;
                    *(u16x8*)&Ash[kcA][o][0] = *(const u16x8*)&awh[aoff];
                    *(u16x8*)&Asl[kcA][o][0] = *(const u16x8*)&awl[aoff];
                }
            }
            {   // stage B: vector loads, no unpack
#pragma unroll
                for (int q = 0; q < 2; q++) {
                    const int sp = spB + 64 * q;
                    u16x8 vh, vl2;
                    if (valid[q]) {
                        const int goff = sbase[q] + c0 + 8 * kcB;
                        vh  = *(const u16x8*)&xh[goff];
                        vl2 = *(const u16x8*)&xl[goff];
                    } else {
#pragma unroll
                        for (int j = 0; j < 8; j++) { vh[j] = 0; vl2[j] = 0; }
                    }
                    *(u16x8*)&Bsh[sp][8 * kcB] = vh;
                    *(u16x8*)&Bsl[sp][8 * kcB] = vl2;
                }
            }
            __syncthreads();
            bf16x8 bh[4], bl[4];
#pragma unroll
            for (int nf = 0; nf < 4; nf++) {
                const int nn = wc * 64 + nf * 16 + lr;
                bh[nf] = *(const bf16x8*)&Bsh[nn][8 * lq];
                bl[nf] = *(const bf16x8*)&Bsl[nn][8 * lq];
            }
#pragma unroll
            for (int mf = 0; mf < MFR; mf++) {
                const int m = wr * (BM / 2) + mf * 16 + lr;
                bf16x8 ah = *(const bf16x8*)&Ash[lq][m][0];
                bf16x8 al = *(const bf16x8*)&Asl[lq][m][0];
#pragma unroll
                for (int nf = 0; nf < 4; nf++) {
                    acc[mf][nf] = __builtin_amdgcn_mfma_f32_16x16x32_bf16(ah, bh[nf], acc[mf][nf], 0, 0, 0);
                    acc[mf][nf] = __builtin_amdgcn_mfma_f32_16x16x32_bf16(ah, bl[nf], acc[mf][nf], 0, 0, 0);
                    acc[mf][nf] = __builtin_amdgcn_mfma_f32_16x16x32_bf16(al, bh[nf], acc[mf][nf], 0, 0, 0);
                }
            }
        }
    }

    const int HoWo = Ho * Wo;
#pragma unroll
    for (int mf = 0; mf < MFR; mf++) {
        const int obase = o0 + wr * (BM / 2) + mf * 16 + 4 * lq;
        const float4 b4 = *(const float4*)&bias[obase];
#pragma unroll
        for (int nf = 0; nf < 4; nf++) {
            const int s = s0 + wc * 64 + nf * 16 + lr;
            const int n = s >> lgGHW;
            const int r = s & ghwm;
            const int u = r >> lgGW, v = r & gwm;
            const int U = DEC ? 2 * u + pi : u;
            const int V = DEC ? 2 * v + pj : v;
            const size_t yidx = ((size_t)(n * Ho + U) * Wo + V) * O + obase;
            float vals[4];
            vals[0] = acc[mf][nf][0] + b4.x;
            vals[1] = acc[mf][nf][1] + b4.y;
            vals[2] = acc[mf][nf][2] + b4.z;
            vals[3] = acc[mf][nf][3] + b4.w;
            u16x4 hv, lv;
#pragma unroll
            for (int i = 0; i < 4; i++) {
                float val = vals[i];
                val = (act == 0) ? fmaxf(val, 0.f) : 1.f / (1.f + expf(-val));
                vals[i] = val;
                ushort h = f2bf(val);
                hv[i] = h;
                lv[i] = f2bf(val - bf2f(h));
            }
            *(u16x4*)&yh[yidx] = hv;
            *(u16x4*)&yl[yidx] = lv;
            if (fout) {
#pragma unroll
                for (int i = 0; i < 4; i++)
                    fout[(size_t)n * O * HoWo + (size_t)(obase + i) * HoWo + U * Wo + V] = vals[i];
            }
        }
    }
}

// ---------------------------------------------------------------------------
// dconv4: x NHWC split (256,32,32,128) -> y(256,3,64,64) fp32, sigmoid.
// One thread = 2x2 output parity block. 32-channel groups: per neighbor,
// 4 back-to-back u16x8 loads per plane (full 64B line), fp32 once.
// grid (4, 256), block 256.
// ---------------------------------------------------------------------------
__device__ __forceinline__ void load32f(float* d, const ushort* hp,
                                        const ushort* lp, bool ok)
{
    if (ok) {
#pragma unroll
        for (int qg = 0; qg < 4; qg++) {
            u16x8 h = *(const u16x8*)(hp + 8 * qg);
            u16x8 l = *(const u16x8*)(lp + 8 * qg);
#pragma unroll
            for (int j = 0; j < 8; j++) d[8 * qg + j] = bf2f(h[j]) + bf2f(l[j]);
        }
    } else {
#pragma unroll
        for (int j = 0; j < 32; j++) d[j] = 0.f;
    }
}

__global__ __launch_bounds__(256)
void dconv4_kernel(const ushort* __restrict__ xh, const ushort* __restrict__ xl,
                   const float* __restrict__ W, const float* __restrict__ bias,
                   float* __restrict__ y)
{
    __shared__ float ws[3456];   // W[o][c][kh*3+kw], o stride 1152
    const int tid = threadIdx.x;
    for (int i = tid; i < 3456; i += 256) ws[i] = W[i];
    __syncthreads();
    const int n = blockIdx.y;
    const int pos = blockIdx.x * 256 + tid;   // u*32+v
    const int u = pos >> 5, v = pos & 31;

    float acc[2][2][3];
#pragma unroll
    for (int pi_ = 0; pi_ < 2; pi_++)
#pragma unroll
        for (int pj_ = 0; pj_ < 2; pj_++)
#pragma unroll
            for (int o = 0; o < 3; o++) acc[pi_][pj_][o] = bias[o];

    const size_t b00 = ((size_t)n * 1024 + pos) * 128;
    const size_t b10 = b00 - 4096;   // (u-1, v)
    const size_t b01 = b00 - 128;    // (u, v-1)
    const size_t b11 = b00 - 4224;   // (u-1, v-1)
    const bool vu = (u > 0), vv = (v > 0);

    float xf[32];
    for (int kcg = 0; kcg < 4; kcg++) {
        const int co = kcg * 32;
        // x00: taps w[8]->[0][0], w[7]->[0][1], w[5]->[1][0], w[4]->[1][1]
        load32f(xf, &xh[b00 + co], &xl[b00 + co], true);
#pragma unroll
        for (int j = 0; j < 32; j++) {
            const int c9 = (co + j) * 9;
#pragma unroll
            for (int o = 0; o < 3; o++) {
                const float* w = &ws[o * 1152 + c9];
                acc[0][0][o] = fmaf(xf[j], w[8], acc[0][0][o]);
                acc[0][1][o] = fmaf(xf[j], w[7], acc[0][1][o]);
                acc[1][0][o] = fmaf(xf[j], w[5], acc[1][0][o]);
                acc[1][1][o] = fmaf(xf[j], w[4], acc[1][1][o]);
            }
        }
        // x01 (u, v-1): w[6]->[0][0], w[3]->[1][0]
        load32f(xf, &xh[b01 + co], &xl[b01 + co], vv);
#pragma unroll
        for (int j = 0; j < 32; j++) {
            const int c9 = (co + j) * 9;
#pragma unroll
            for (int o = 0; o < 3; o++) {
                const float* w = &ws[o * 1152 + c9];
                acc[0][0][o] = fmaf(xf[j], w[6], acc[0][0][o]);
                acc[1][0][o] = fmaf(xf[j], w[3], acc[1][0][o]);
            }
        }
        // x10 (u-1, v): w[2]->[0][0], w[1]->[0][1]
        load32f(xf, &xh[b10 + co], &xl[b10 + co], vu);
#pragma unroll
        for (int j = 0; j < 32; j++) {
            const int c9 = (co + j) * 9;
#pragma unroll
            for (int o = 0; o < 3; o++) {
                const float* w = &ws[o * 1152 + c9];
                acc[0][0][o] = fmaf(xf[j], w[2], acc[0][0][o]);
                acc[0][1][o] = fmaf(xf[j], w[1], acc[0][1][o]);
            }
        }
        // x11 (u-1, v-1): w[0]->[0][0]
        load32f(xf, &xh[b11 + co], &xl[b11 + co], vu && vv);
#pragma unroll
        for (int j = 0; j < 32; j++) {
            const int c9 = (co + j) * 9;
#pragma unroll
            for (int o = 0; o < 3; o++)
                acc[0][0][o] = fmaf(xf[j], ws[o * 1152 + c9], acc[0][0][o]);
        }
    }
#pragma unroll
    for (int o = 0; o < 3; o++)
#pragma unroll
        for (int pi_ = 0; pi_ < 2; pi_++) {
            float2 val;
            val.x = 1.f / (1.f + expf(-acc[pi_][0][o]));
            val.y = 1.f / (1.f + expf(-acc[pi_][1][o]));
            *(float2*)&y[(size_t)n * 12288 + o * 4096 + (2 * u + pi_) * 64 + 2 * v] = val;
        }
}

// ---------------------------------------------------------------------------
// rownorm[r] = ||row_r||^2 over 4096 cols. grid 256, block 64.
// ---------------------------------------------------------------------------
__global__ __launch_bounds__(64)
void pnorm_kernel(const float* __restrict__ rows, float* __restrict__ norms)
{
    const int r = blockIdx.x, lane = threadIdx.x;
    const float* pr = rows + (size_t)r * 4096;
    float s = 0.f;
    for (int d = lane; d < 4096; d += 64) s = fmaf(pr[d], pr[d], s);
#pragma unroll
    for (int off = 32; off; off >>= 1) s += __shfl_xor(s, off);
    if (lane == 0) norms[r] = s;
}

// ---------------------------------------------------------------------------
// Split-K partial dots: dotpart[ks][b][gp]. grid (64,8), block 256.
// ---------------------------------------------------------------------------
__global__ __launch_bounds__(256)
void dists_part_kernel(const float* __restrict__ latent, const float* __restrict__ protos,
                       float* __restrict__ dotpart)
{
    __shared__ float zl[4][512];
    const int b0 = blockIdx.x * 4, ks = blockIdx.y, tid = threadIdx.x;
    for (int i = tid; i < 512; i += 256) {
        int bb = i >> 7, off = i & 127;
        ((float4*)&zl[bb][0])[off] =
            ((const float4*)(latent + (size_t)(b0 + bb) * 4096 + ks * 512))[off];
    }
    __syncthreads();
    const int w = tid >> 6, lane = tid & 63;
    for (int i = 0; i < 64; i++) {
        const int gp = w * 64 + i;
        const float* pr = protos + (size_t)gp * 4096 + ks * 512;
        float dot[4] = {0.f, 0.f, 0.f, 0.f};
#pragma unroll
        for (int d8 = 0; d8 < 8; d8++) {
            const int d = lane + 64 * d8;
            const float pv = pr[d];
#pragma unroll
            for (int bb = 0; bb < 4; bb++) dot[bb] = fmaf(zl[bb][d], pv, dot[bb]);
        }
#pragma unroll
        for (int bb = 0; bb < 4; bb++)
#pragma unroll
            for (int off = 32; off; off >>= 1) dot[bb] += __shfl_xor(dot[bb], off);
        if (lane == 0) {
#pragma unroll
            for (int bb = 0; bb < 4; bb++)
                dotpart[(size_t)ks * 65536 + (size_t)(b0 + bb) * 256 + gp] = dot[bb];
        }
    }
}

__global__ __launch_bounds__(256)
void dists_final_kernel(const float* __restrict__ dotpart, const float* __restrict__ znorm,
                        const float* __restrict__ pnorm, float* __restrict__ dists)
{
    const int i = blockIdx.x * 256 + threadIdx.x;
    const int b = i >> 8, gp = i & 255;
    float s = 0.f;
#pragma unroll
    for (int ks = 0; ks < 8; ks++) s += dotpart[(size_t)ks * 65536 + i];
    dists[i] = znorm[b] + pnorm[gp] - 2.f * s;
}

// ---------------------------------------------------------------------------
// softmin + mix. grid (64 bgroups, 16 dchunks), block 256.
// Also writes mixed as NHWC split planes for dconv1.
// ---------------------------------------------------------------------------
__global__ __launch_bounds__(256)
void softmix_kernel(const float* __restrict__ dists, const float* __restrict__ protos,
                    const float* __restrict__ pw, float* __restrict__ mixed,
                    ushort* __restrict__ mh, ushort* __restrict__ ml)
{
    __shared__ float sml[4][256];
    const int b0 = blockIdx.x * 4, d0 = blockIdx.y * 256, tid = threadIdx.x;
    const int w = tid >> 6, lane = tid & 63;
#pragma unroll
    for (int g = 0; g < 4; g++) {
        float dv = -dists[(size_t)(b0 + w) * 256 + g * 64 + lane];
        float m = dv;
#pragma unroll
        for (int off = 32; off; off >>= 1) m = fmaxf(m, __shfl_xor(m, off));
        float e = expf(dv - m);
        float s = e;
#pragma unroll
        for (int off = 32; off; off >>= 1) s += __shfl_xor(s, off);
        sml[w][g * 64 + lane] = e / s;
    }
    __syncthreads();
    const int d = d0 + tid;
    const int oo = d >> 4, sp = d & 15;   // NCHW d -> (o, site)
    float accg[4][4];
#pragma unroll
    for (int bb = 0; bb < 4; bb++)
#pragma unroll
        for (int g = 0; g < 4; g++) accg[bb][g] = 0.f;
#pragma unroll
    for (int g = 0; g < 4; g++)
        for (int p = 0; p < 64; p++) {
            float pv = protos[(size_t)(g * 64 + p) * 4096 + d];
#pragma unroll
            for (int bb = 0; bb < 4; bb++)
                accg[bb][g] = fmaf(sml[bb][g * 64 + p], pv, accg[bb][g]);
        }
    float pwv[4];
#pragma unroll
    for (int g = 0; g < 4; g++) pwv[g] = pw[g * 4096 + d];
#pragma unroll
    for (int bb = 0; bb < 4; bb++) {
        float m = 0.f;
#pragma unroll
        for (int g = 0; g < 4; g++) m = fmaf(pwv[g], accg[bb][g], m);
        m *= 0.25f;
        mixed[(size_t)(b0 + bb) * 4096 + d] = m;
        const size_t pidx = ((size_t)(b0 + bb) * 16 + sp) * 256 + oo;
        ushort h = f2bf(m);
        mh[pidx] = h;
        ml[pidx] = f2bf(m - bf2f(h));
    }
}

// ============================================================================
extern "C" void kernel_launch(void* const* d_in, const int* in_sizes, int n_in,
                              void* d_out, int out_size, void* d_ws, size_t ws_size,
                              hipStream_t stream)
{
    const float* x    = (const float*)d_in[0];
    const float* We1  = (const float*)d_in[1];  const float* be1 = (const float*)d_in[2];
    const float* We2  = (const float*)d_in[3];  const float* be2 = (const float*)d_in[4];
    const float* We3  = (const float*)d_in[5];  const float* be3 = (const float*)d_in[6];
    const float* We4  = (const float*)d_in[7];  const float* be4 = (const float*)d_in[8];
    const float* Wd1  = (const float*)d_in[9];  const float* bd1 = (const float*)d_in[10];
    const float* Wd2  = (const float*)d_in[11]; const float* bd2 = (const float*)d_in[12];
    const float* Wd3  = (const float*)d_in[13]; const float* bd3 = (const float*)d_in[14];
    const float* Wd4  = (const float*)d_in[15]; const float* bd4 = (const float*)d_in[16];
    const float* protos = (const float*)d_in[17];
    const float* pw   = (const float*)d_in[18];

    float* out = (float*)d_out;
    float* recon_img   = out;               // (256,3,64,64)
    float* recon_proto = out + 3145728;     // (256,3,64,64)
    float* dists       = out + 6291456;     // (256,4,64)
    float* latent      = out + 6356992;     // (256,256,4,4) fp32 NCHW
    float* out_protos  = out + 7405568;     // (4,64,4096)
    float* mixed       = out + 8454144;     // (256,4096)

    ushort* wsu  = (ushort*)d_ws;
    ushort* bufAh = wsu;                    // 33,554,432 each plane
    ushort* bufAl = bufAh + 33554432;
    ushort* bufBh = bufAl + 33554432;       //  8,388,608
    ushort* bufBl = bufBh + 8388608;
    ushort* bufCh = bufBl + 8388608;        //  2,097,152
    ushort* bufCl = bufCh + 2097152;
    ushort* bufLh = bufCl + 2097152;        //  1,048,576
    ushort* bufLl = bufLh + 1048576;
    ushort* bufMh = bufLl + 1048576;        //  1,048,576
    ushort* bufMl = bufMh + 1048576;
    ushort* wc2h = bufMl + 1048576;         //    147,456 each
    ushort* wc2l = wc2h + 147456;
    ushort* wc3h = wc2l + 147456;
    ushort* wc3l = wc3h + 147456;
    ushort* wc4h = wc3l + 147456;           //    294,912 each
    ushort* wc4l = wc4h + 294912;
    ushort* wd1h = wc4l + 294912;           //    294,912 each
    ushort* wd1l = wd1h + 294912;
    ushort* wd2h = wd1l + 294912;           //    147,456 each
    ushort* wd2l = wd2h + 147456;
    ushort* wd3h = wd2l + 147456;
    ushort* wd3l = wd3h + 147456;
    float* pnorm = (float*)(wd3l + 147456); //        256
    float* znorm = pnorm + 256;             //        256
    float* dotpart = znorm + 256;           //    524,288

    // weight repack+split (d_ws re-poisoned every call -> redo every call)
    repack_kernel<<<576, 256, 0, stream>>>(We2, wc2h, wc2l, 128, 128);
    repack_kernel<<<576, 256, 0, stream>>>(We3, wc3h, wc3l, 128, 128);
    repack_kernel<<<1152, 256, 0, stream>>>(We4, wc4h, wc4l, 256, 128);
    repack_kernel<<<1152, 256, 0, stream>>>(Wd1, wd1h, wd1l, 128, 256);
    repack_kernel<<<576, 256, 0, stream>>>(Wd2, wd2h, wd2l, 128, 128);
    repack_kernel<<<576, 256, 0, stream>>>(Wd3, wd3h, wd3l, 128, 128);
    pnorm_kernel<<<256, 64, 0, stream>>>(protos, pnorm);

    // encoder
    conv1_kernel<<<dim3(256, 4), 256, 0, stream>>>(x, We1, be1, bufAh, bufAl);
    conv_mfma<false, 128><<<dim3(512, 1), 256, 0, stream>>>(
        bufAh, bufAl, wc2h, wc2l, be2, bufBh, bufBl, nullptr,
        128, 32, 32, 128, 16, 16, 4, 8, 0);
    conv_mfma<false, 64><<<dim3(128, 2), 256, 0, stream>>>(
        bufBh, bufBl, wc3h, wc3l, be3, bufCh, bufCl, nullptr,
        128, 16, 16, 128, 8, 8, 3, 6, 0);
    conv_mfma<false, 64><<<dim3(32, 4), 256, 0, stream>>>(
        bufCh, bufCl, wc4h, wc4l, be4, bufLh, bufLl, latent,
        128, 8, 8, 256, 4, 4, 2, 4, 1);

    // prototype block (fp32)
    pnorm_kernel<<<256, 64, 0, stream>>>(latent, znorm);
    dists_part_kernel<<<dim3(64, 8), 256, 0, stream>>>(latent, protos, dotpart);
    dists_final_kernel<<<256, 256, 0, stream>>>(dotpart, znorm, pnorm, dists);
    softmix_kernel<<<dim3(64, 16), 256, 0, stream>>>(dists, protos, pw, mixed,
                                                     bufMh, bufMl);
    hipMemcpyAsync(out_protos, protos, 1048576 * sizeof(float),
                   hipMemcpyDeviceToDevice, stream);

    // two decoders (share scratch; stream order serializes)
    for (int pass = 0; pass < 2; pass++) {
        const ushort* sh = (pass == 0) ? bufMh : bufLh;
        const ushort* sl = (pass == 0) ? bufMl : bufLl;
        float* dst = (pass == 0) ? recon_proto : recon_img;
        conv_mfma<true, 64><<<dim3(32, 2, 4), 256, 0, stream>>>(
            sh, sl, wd1h, wd1l, bd1, bufCh, bufCl, nullptr,
            256, 4, 4, 128, 8, 8, 2, 4, 0);
        conv_mfma<true, 128><<<dim3(128, 1, 4), 256, 0, stream>>>(
            bufCh, bufCl, wd2h, wd2l, bd2, bufBh, bufBl, nullptr,
            128, 8, 8, 128, 16, 16, 3, 6, 0);
        conv_mfma<true, 128><<<dim3(512, 1, 4), 256, 0, stream>>>(
            bufBh, bufBl, wd3h, wd3l, bd3, bufAh, bufAl, nullptr,
            128, 16, 16, 128, 32, 32, 4, 8, 0);
        dconv4_kernel<<<dim3(4, 256), 256, 0, stream>>>(bufAh, bufAl, Wd4, bd4, dst);
    }
}

// Round 10
// 1019.903 us; speedup vs baseline: 3.3946x; 3.3946x over previous
//
#include <hip/hip_runtime.h>
#include <hip/hip_bf16.h>
#include <cmath>

// ============================================================================
// RAE forward, round 10 (= round-8/9 source, unexecuted due to GPU timeouts).
// NHWC split-plane bf16x3 MFMA convs.
// dconv4 = LDS-staged band kernel:
//   - block = (band of 2 input site-rows, n); stages 3 input rows to LDS as
//     fp32 (hi+lo combined), globally contiguous loads -> no over-fetch.
//   - 4 threads/site, thread q owns channels c=4j+q; 2-way (free) LDS banking
//     via row stride 132; weights ws2[c][28] (disjoint bank groups per q).
//   - 12 accs/thread, cross-q shfl_xor reduce; tap mapping = validated round 6.
// Everything else identical to round 7 (validated).
// ============================================================================

typedef short  bf16x8 __attribute__((ext_vector_type(8)));
typedef float  f32x4  __attribute__((ext_vector_type(4)));
typedef ushort u16x8  __attribute__((ext_vector_type(8)));
typedef ushort u16x4  __attribute__((ext_vector_type(4)));

__device__ __forceinline__ ushort f2bf(float f) {
    uint u = __float_as_uint(f);
    return (ushort)((u + 0x7fffu + ((u >> 16) & 1u)) >> 16);   // RNE
}
__device__ __forceinline__ float bf2f(ushort h) {
    return __uint_as_float(((uint)h) << 16);                   // exact
}

// ---------------------------------------------------------------------------
// repack + split: wh/wl[((t*(C/8)+kcg)*O+o)*8+j] = hi/lo(W[o][8kcg+j][t])
// ---------------------------------------------------------------------------
__global__ __launch_bounds__(256)
void repack_kernel(const float* __restrict__ W, ushort* __restrict__ wh,
                   ushort* __restrict__ wl, int O, int C)
{
    int i = blockIdx.x * 256 + threadIdx.x;
    if (i >= O * C * 9) return;
    int j = i & 7;
    int rest = i >> 3;
    int o = rest % O;
    int rest2 = rest / O;
    int C8 = C >> 3;
    int kcg = rest2 % C8;
    int t = rest2 / C8;
    float v = W[(o * C + 8 * kcg + j) * 9 + t];
    ushort h = f2bf(v);
    wh[i] = h;
    wl[i] = f2bf(v - bf2f(h));
}

// ---------------------------------------------------------------------------
// conv1: x(256,3,64,64) fp32 -> y NHWC split (256,32,32,128), relu.
// grid (B, 4 site-quarters), block 256; thread = one site, all 128 o.
// ---------------------------------------------------------------------------
__global__ __launch_bounds__(256)
void conv1_kernel(const float* __restrict__ x, const float* __restrict__ W,
                  const float* __restrict__ bias, ushort* __restrict__ yh,
                  ushort* __restrict__ yl)
{
    __shared__ float xs[3 * 64 * 64];   // 48 KB
    __shared__ float ws[128 * 27];      // 13.5 KB
    __shared__ float bs[128];
    const int n = blockIdx.x, q = blockIdx.y;
    const int tid = threadIdx.x;
    const float* xp = x + (size_t)n * 3 * 64 * 64;
    for (int i = tid; i < 3 * 64 * 64 / 4; i += 256)
        ((float4*)xs)[i] = ((const float4*)xp)[i];
    for (int i = tid; i < 128 * 27; i += 256) ws[i] = W[i];
    if (tid < 128) bs[tid] = bias[tid];
    __syncthreads();

    const int pos = q * 256 + tid;        // site u*32+v
    const int u = pos >> 5, v = pos & 31;
    float xv[27];
#pragma unroll
    for (int c = 0; c < 3; c++)
#pragma unroll
        for (int kh = 0; kh < 3; kh++)
#pragma unroll
            for (int kw = 0; kw < 3; kw++) {
                int iu = 2 * u - 1 + kh, iv = 2 * v - 1 + kw;
                bool ok = (iu >= 0) & (iu < 64) & (iv >= 0) & (iv < 64);
                xv[c * 9 + kh * 3 + kw] = ok ? xs[(c << 12) + (iu << 6) + iv] : 0.f;
            }
    const size_t base = ((size_t)n * 1024 + pos) * 128;
#pragma unroll
    for (int og = 0; og < 4; og++) {
        u16x8 hv[4], lv[4];
#pragma unroll
        for (int oq = 0; oq < 4; oq++) {
#pragma unroll
            for (int oi = 0; oi < 8; oi++) {
                const int o = og * 32 + oq * 8 + oi;
                float acc = bs[o];
#pragma unroll
                for (int t = 0; t < 27; t++) acc = fmaf(xv[t], ws[o * 27 + t], acc);
                acc = fmaxf(acc, 0.f);
                ushort h = f2bf(acc);
                hv[oq][oi] = h;
                lv[oq][oi] = f2bf(acc - bf2f(h));
            }
        }
#pragma unroll
        for (int oq = 0; oq < 4; oq++) {
            *(u16x8*)&yh[base + og * 32 + 8 * oq] = hv[oq];
            *(u16x8*)&yl[base + og * 32 + 8 * oq] = lv[oq];
        }
    }
}

// ---------------------------------------------------------------------------
// MFMA implicit-GEMM conv (bf16x3, NHWC split planes). BM in {64,128}, BN=128.
// (unchanged from validated round 6/7)
// ---------------------------------------------------------------------------
template<bool DEC, int BM>
__global__ __launch_bounds__(256)
void conv_mfma(const ushort* __restrict__ xh, const ushort* __restrict__ xl,
               const ushort* __restrict__ awh, const ushort* __restrict__ awl,
               const float* __restrict__ bias,
               ushort* __restrict__ yh, ushort* __restrict__ yl,
               float* __restrict__ fout,
               int C, int Hi, int Wi, int O, int Ho, int Wo,
               int lgGW, int lgGHW, int act)
{
    constexpr int MFR = BM / 32;
    constexpr int ACH = BM / 64;
    __shared__ __align__(16) ushort Ash[4][BM][8];
    __shared__ __align__(16) ushort Asl[4][BM][8];
    __shared__ __align__(16) ushort Bsh[128][40];
    __shared__ __align__(16) ushort Bsl[128][40];

    const int tid = threadIdx.x;
    const int lane = tid & 63, wv = tid >> 6;
    const int wr = wv >> 1, wc = wv & 1;
    const int lr = lane & 15, lq = lane >> 4;

    const int o0 = blockIdx.y * BM;
    const int s0 = blockIdx.x * 128;

    int pi = 0, pj = 0, ntv = 0, nth = 0;
    if (DEC) {
        pi = blockIdx.z >> 1; pj = blockIdx.z & 1;
        ntv = (pi == 1) ? 1 : 2;
        nth = (pj == 1) ? 1 : 2;
    }
    const int gwm = (1 << lgGW) - 1, ghwm = (1 << lgGHW) - 1;
    const int C8 = C >> 3;

    const int kcB = tid & 3;
    const int spB = tid >> 2;          // 0..63
    int nS[2], uS[2], vS[2];
#pragma unroll
    for (int q = 0; q < 2; q++) {
        int s = s0 + spB + 64 * q;
        nS[q] = s >> lgGHW;
        int r = s & ghwm;
        uS[q] = r >> lgGW;
        vS[q] = r & gwm;
    }
    const int kcA = tid >> 6;
    const int oA = tid & 63;

    f32x4 acc[MFR][4] = {};

    const int ntaps = DEC ? ntv * nth : 9;
    for (int t = 0; t < ntaps; t++) {
        int tapidx;
        int sbase[2]; bool valid[2];
        if (!DEC) {
            int kh = t / 3, kw = t % 3;
            tapidx = t;
#pragma unroll
            for (int q = 0; q < 2; q++) {
                int iu = 2 * uS[q] - 1 + kh, iv = 2 * vS[q] - 1 + kw;
                valid[q] = (iu >= 0) & (iu < Hi) & (iv >= 0) & (iv < Wi);
                sbase[q] = ((nS[q] * Hi + iu) * Wi + iv) * C;
            }
        } else {
            int itv = t / nth, ith = t - (t / nth) * nth;
            int kh = (pi == 1) ? 1 : 2 - 2 * itv;   // da = itv
            int kw = (pj == 1) ? 1 : 2 - 2 * ith;   // db = ith
            tapidx = kh * 3 + kw;
#pragma unroll
            for (int q = 0; q < 2; q++) {
                int a = uS[q] - itv, b2 = vS[q] - ith;
                valid[q] = (a >= 0) & (b2 >= 0);
                sbase[q] = ((nS[q] * Hi + a) * Wi + b2) * C;
            }
        }
        const size_t wtap = (size_t)tapidx * C8 * O * 8;
        for (int c0 = 0; c0 < C; c0 += 32) {
            __syncthreads();   // WAR: previous step's frag reads done
            {   // stage A: pure 16B copies
                const size_t koff = wtap + (size_t)((c0 >> 3) + kcA) * O * 8;
#pragma unroll
                for (int q = 0; q < ACH; q++) {
                    const int o = oA + 64 * q;
                    const size_t aoff = koff + (size_t)(o0 + o) * 8;
                    *(u16x8*)&Ash[kcA][o][0] = *(const u16x8*)&awh[aoff];
                    *(u16x8*)&Asl[kcA][o][0] = *(const u16x8*)&awl[aoff];
                }
            }
            {   // stage B: vector loads, no unpack
#pragma unroll
                for (int q = 0; q < 2; q++) {
                    const int sp = spB + 64 * q;
                    u16x8 vh, vl2;
                    if (valid[q]) {
                        const int goff = sbase[q] + c0 + 8 * kcB;
                        vh  = *(const u16x8*)&xh[goff];
                        vl2 = *(const u16x8*)&xl[goff];
                    } else {
#pragma unroll
                        for (int j = 0; j < 8; j++) { vh[j] = 0; vl2[j] = 0; }
                    }
                    *(u16x8*)&Bsh[sp][8 * kcB] = vh;
                    *(u16x8*)&Bsl[sp][8 * kcB] = vl2;
                }
            }
            __syncthreads();
            bf16x8 bh[4], bl[4];
#pragma unroll
            for (int nf = 0; nf < 4; nf++) {
                const int nn = wc * 64 + nf * 16 + lr;
                bh[nf] = *(const bf16x8*)&Bsh[nn][8 * lq];
                bl[nf] = *(const bf16x8*)&Bsl[nn][8 * lq];
            }
#pragma unroll
            for (int mf = 0; mf < MFR; mf++) {
                const int m = wr * (BM / 2) + mf * 16 + lr;
                bf16x8 ah = *(const bf16x8*)&Ash[lq][m][0];
                bf16x8 al = *(const bf16x8*)&Asl[lq][m][0];
#pragma unroll
                for (int nf = 0; nf < 4; nf++) {
                    acc[mf][nf] = __builtin_amdgcn_mfma_f32_16x16x32_bf16(ah, bh[nf], acc[mf][nf], 0, 0, 0);
                    acc[mf][nf] = __builtin_amdgcn_mfma_f32_16x16x32_bf16(ah, bl[nf], acc[mf][nf], 0, 0, 0);
                    acc[mf][nf] = __builtin_amdgcn_mfma_f32_16x16x32_bf16(al, bh[nf], acc[mf][nf], 0, 0, 0);
                }
            }
        }
    }

    const int HoWo = Ho * Wo;
#pragma unroll
    for (int mf = 0; mf < MFR; mf++) {
        const int obase = o0 + wr * (BM / 2) + mf * 16 + 4 * lq;
        const float4 b4 = *(const float4*)&bias[obase];
#pragma unroll
        for (int nf = 0; nf < 4; nf++) {
            const int s = s0 + wc * 64 + nf * 16 + lr;
            const int n = s >> lgGHW;
            const int r = s & ghwm;
            const int u = r >> lgGW, v = r & gwm;
            const int U = DEC ? 2 * u + pi : u;
            const int V = DEC ? 2 * v + pj : v;
            const size_t yidx = ((size_t)(n * Ho + U) * Wo + V) * O + obase;
            float vals[4];
            vals[0] = acc[mf][nf][0] + b4.x;
            vals[1] = acc[mf][nf][1] + b4.y;
            vals[2] = acc[mf][nf][2] + b4.z;
            vals[3] = acc[mf][nf][3] + b4.w;
            u16x4 hv, lv;
#pragma unroll
            for (int i = 0; i < 4; i++) {
                float val = vals[i];
                val = (act == 0) ? fmaxf(val, 0.f) : 1.f / (1.f + expf(-val));
                vals[i] = val;
                ushort h = f2bf(val);
                hv[i] = h;
                lv[i] = f2bf(val - bf2f(h));
            }
            *(u16x4*)&yh[yidx] = hv;
            *(u16x4*)&yl[yidx] = lv;
            if (fout) {
#pragma unroll
                for (int i = 0; i < 4; i++)
                    fout[(size_t)n * O * HoWo + (size_t)(obase + i) * HoWo + U * Wo + V] = vals[i];
            }
        }
    }
}

// ---------------------------------------------------------------------------
// dconv4: x NHWC split (256,32,32,128) -> y(256,3,64,64) fp32, sigmoid.
// LDS-staged band kernel. grid (16, 256), block 256.
// ---------------------------------------------------------------------------
__global__ __launch_bounds__(256)
void dconv4_kernel(const ushort* __restrict__ xh, const ushort* __restrict__ xl,
                   const float* __restrict__ W, const float* __restrict__ bias,
                   float* __restrict__ y)
{
    __shared__ float xs[3][32][132];   // 50.7 KB; stride 132 -> 2-way banks (free)
    __shared__ float ws2[128][28];     // [c][t*3+o], row 112B (16B-aligned)
    const int tid = threadIdx.x;
    const int n = blockIdx.y, bx = blockIdx.x;

    // weights: ws2[c][t*3+o] = W[o][c][t]
    for (int i = tid; i < 3456; i += 256) {
        const int o = i / 1152, rem = i - o * 1152;
        const int c = rem / 9, t = rem - c * 9;
        ws2[c][t * 3 + o] = W[i];
    }
    // stage 3 input rows (combined hi+lo), contiguous global reads
    const int gr0 = 2 * bx - 1;
#pragma unroll
    for (int k = 0; k < 6; k++) {
        const int e = (tid + 256 * k) * 8;    // 0..12280
        const int ir = e >> 12;               // 0..2
        const int rv = e & 4095;              // v*128 + c
        const int giu = gr0 + ir;
        float o0, o1, o2, o3, o4, o5, o6, o7;
        if (giu >= 0) {
            const size_t g = (size_t)(n * 32 + giu) * 4096 + rv;
            u16x8 h = *(const u16x8*)&xh[g];
            u16x8 l = *(const u16x8*)&xl[g];
            o0 = bf2f(h[0]) + bf2f(l[0]); o1 = bf2f(h[1]) + bf2f(l[1]);
            o2 = bf2f(h[2]) + bf2f(l[2]); o3 = bf2f(h[3]) + bf2f(l[3]);
            o4 = bf2f(h[4]) + bf2f(l[4]); o5 = bf2f(h[5]) + bf2f(l[5]);
            o6 = bf2f(h[6]) + bf2f(l[6]); o7 = bf2f(h[7]) + bf2f(l[7]);
        } else {
            o0 = o1 = o2 = o3 = o4 = o5 = o6 = o7 = 0.f;
        }
        float* d = &xs[ir][rv >> 7][rv & 127];
        d[0] = o0; d[1] = o1; d[2] = o2; d[3] = o3;
        d[4] = o4; d[5] = o5; d[6] = o6; d[7] = o7;
    }
    __syncthreads();

    const int s = tid >> 2, q = tid & 3;
    const int urow = s >> 5, v = s & 31;
    const int ir1 = urow + 1;                 // own input row in LDS
    const bool vok = (v > 0);
    const int vm = vok ? v - 1 : 0;

    float a00[3] = {0.f, 0.f, 0.f}, a01[3] = {0.f, 0.f, 0.f};
    float a10[3] = {0.f, 0.f, 0.f}, a11[3] = {0.f, 0.f, 0.f};

#pragma unroll 4
    for (int j = 0; j < 32; j++) {
        const int c = 4 * j + q;
        const float x00 = xs[ir1][v][c];
        const float x01 = vok ? xs[ir1][vm][c] : 0.f;
        const float x10 = xs[ir1 - 1][v][c];
        const float x11 = vok ? xs[ir1 - 1][vm][c] : 0.f;
        const float* w = &ws2[c][0];          // w[t*3+o]
#pragma unroll
        for (int o = 0; o < 3; o++) {
            a00[o] = fmaf(x00, w[24 + o], a00[o]);   // t=8
            a00[o] = fmaf(x01, w[18 + o], a00[o]);   // t=6
            a00[o] = fmaf(x10, w[6 + o],  a00[o]);   // t=2
            a00[o] = fmaf(x11, w[o],      a00[o]);   // t=0
            a01[o] = fmaf(x00, w[21 + o], a01[o]);   // t=7
            a01[o] = fmaf(x10, w[3 + o],  a01[o]);   // t=1
            a10[o] = fmaf(x00, w[15 + o], a10[o]);   // t=5
            a10[o] = fmaf(x01, w[9 + o],  a10[o]);   // t=3
            a11[o] = fmaf(x00, w[12 + o], a11[o]);   // t=4
        }
    }
    // reduce across the 4 q-lanes of each site
#pragma unroll
    for (int o = 0; o < 3; o++) {
        a00[o] += __shfl_xor(a00[o], 1); a00[o] += __shfl_xor(a00[o], 2);
        a01[o] += __shfl_xor(a01[o], 1); a01[o] += __shfl_xor(a01[o], 2);
        a10[o] += __shfl_xor(a10[o], 1); a10[o] += __shfl_xor(a10[o], 2);
        a11[o] += __shfl_xor(a11[o], 1); a11[o] += __shfl_xor(a11[o], 2);
    }
    // thread q writes parity (q>>1, q&1), 3 outputs
    const int u = 2 * bx + urow;
    const int U = 2 * u + (q >> 1), V = 2 * v + (q & 1);
#pragma unroll
    for (int o = 0; o < 3; o++) {
        float t0 = (q & 2) ? ((q & 1) ? a11[o] : a10[o])
                           : ((q & 1) ? a01[o] : a00[o]);
        t0 += bias[o];
        y[(size_t)n * 12288 + o * 4096 + U * 64 + V] = 1.f / (1.f + expf(-t0));
    }
}

// ---------------------------------------------------------------------------
// rownorm[r] = ||row_r||^2 over 4096 cols. grid 256, block 64.
// ---------------------------------------------------------------------------
__global__ __launch_bounds__(64)
void pnorm_kernel(const float* __restrict__ rows, float* __restrict__ norms)
{
    const int r = blockIdx.x, lane = threadIdx.x;
    const float* pr = rows + (size_t)r * 4096;
    float s = 0.f;
    for (int d = lane; d < 4096; d += 64) s = fmaf(pr[d], pr[d], s);
#pragma unroll
    for (int off = 32; off; off >>= 1) s += __shfl_xor(s, off);
    if (lane == 0) norms[r] = s;
}

// ---------------------------------------------------------------------------
// Split-K partial dots: dotpart[ks][b][gp]. grid (64,8), block 256.
// ---------------------------------------------------------------------------
__global__ __launch_bounds__(256)
void dists_part_kernel(const float* __restrict__ latent, const float* __restrict__ protos,
                       float* __restrict__ dotpart)
{
    __shared__ float zl[4][512];
    const int b0 = blockIdx.x * 4, ks = blockIdx.y, tid = threadIdx.x;
    for (int i = tid; i < 512; i += 256) {
        int bb = i >> 7, off = i & 127;
        ((float4*)&zl[bb][0])[off] =
            ((const float4*)(latent + (size_t)(b0 + bb) * 4096 + ks * 512))[off];
    }
    __syncthreads();
    const int w = tid >> 6, lane = tid & 63;
    for (int i = 0; i < 64; i++) {
        const int gp = w * 64 + i;
        const float* pr = protos + (size_t)gp * 4096 + ks * 512;
        float dot[4] = {0.f, 0.f, 0.f, 0.f};
#pragma unroll
        for (int d8 = 0; d8 < 8; d8++) {
            const int d = lane + 64 * d8;
            const float pv = pr[d];
#pragma unroll
            for (int bb = 0; bb < 4; bb++) dot[bb] = fmaf(zl[bb][d], pv, dot[bb]);
        }
#pragma unroll
        for (int bb = 0; bb < 4; bb++)
#pragma unroll
            for (int off = 32; off; off >>= 1) dot[bb] += __shfl_xor(dot[bb], off);
        if (lane == 0) {
#pragma unroll
            for (int bb = 0; bb < 4; bb++)
                dotpart[(size_t)ks * 65536 + (size_t)(b0 + bb) * 256 + gp] = dot[bb];
        }
    }
}

__global__ __launch_bounds__(256)
void dists_final_kernel(const float* __restrict__ dotpart, const float* __restrict__ znorm,
                        const float* __restrict__ pnorm, float* __restrict__ dists)
{
    const int i = blockIdx.x * 256 + threadIdx.x;
    const int b = i >> 8, gp = i & 255;
    float s = 0.f;
#pragma unroll
    for (int ks = 0; ks < 8; ks++) s += dotpart[(size_t)ks * 65536 + i];
    dists[i] = znorm[b] + pnorm[gp] - 2.f * s;
}

// ---------------------------------------------------------------------------
// softmin + mix. grid (64 bgroups, 16 dchunks), block 256.
// Also writes mixed as NHWC split planes for dconv1.
// ---------------------------------------------------------------------------
__global__ __launch_bounds__(256)
void softmix_kernel(const float* __restrict__ dists, const float* __restrict__ protos,
                    const float* __restrict__ pw, float* __restrict__ mixed,
                    ushort* __restrict__ mh, ushort* __restrict__ ml)
{
    __shared__ float sml[4][256];
    const int b0 = blockIdx.x * 4, d0 = blockIdx.y * 256, tid = threadIdx.x;
    const int w = tid >> 6, lane = tid & 63;
#pragma unroll
    for (int g = 0; g < 4; g++) {
        float dv = -dists[(size_t)(b0 + w) * 256 + g * 64 + lane];
        float m = dv;
#pragma unroll
        for (int off = 32; off; off >>= 1) m = fmaxf(m, __shfl_xor(m, off));
        float e = expf(dv - m);
        float s = e;
#pragma unroll
        for (int off = 32; off; off >>= 1) s += __shfl_xor(s, off);
        sml[w][g * 64 + lane] = e / s;
    }
    __syncthreads();
    const int d = d0 + tid;
    const int oo = d >> 4, sp = d & 15;   // NCHW d -> (o, site)
    float accg[4][4];
#pragma unroll
    for (int bb = 0; bb < 4; bb++)
#pragma unroll
        for (int g = 0; g < 4; g++) accg[bb][g] = 0.f;
#pragma unroll
    for (int g = 0; g < 4; g++)
        for (int p = 0; p < 64; p++) {
            float pv = protos[(size_t)(g * 64 + p) * 4096 + d];
#pragma unroll
            for (int bb = 0; bb < 4; bb++)
                accg[bb][g] = fmaf(sml[bb][g * 64 + p], pv, accg[bb][g]);
        }
    float pwv[4];
#pragma unroll
    for (int g = 0; g < 4; g++) pwv[g] = pw[g * 4096 + d];
#pragma unroll
    for (int bb = 0; bb < 4; bb++) {
        float m = 0.f;
#pragma unroll
        for (int g = 0; g < 4; g++) m = fmaf(pwv[g], accg[bb][g], m);
        m *= 0.25f;
        mixed[(size_t)(b0 + bb) * 4096 + d] = m;
        const size_t pidx = ((size_t)(b0 + bb) * 16 + sp) * 256 + oo;
        ushort h = f2bf(m);
        mh[pidx] = h;
        ml[pidx] = f2bf(m - bf2f(h));
    }
}

// ============================================================================
extern "C" void kernel_launch(void* const* d_in, const int* in_sizes, int n_in,
                              void* d_out, int out_size, void* d_ws, size_t ws_size,
                              hipStream_t stream)
{
    const float* x    = (const float*)d_in[0];
    const float* We1  = (const float*)d_in[1];  const float* be1 = (const float*)d_in[2];
    const float* We2  = (const float*)d_in[3];  const float* be2 = (const float*)d_in[4];
    const float* We3  = (const float*)d_in[5];  const float* be3 = (const float*)d_in[6];
    const float* We4  = (const float*)d_in[7];  const float* be4 = (const float*)d_in[8];
    const float* Wd1  = (const float*)d_in[9];  const float* bd1 = (const float*)d_in[10];
    const float* Wd2  = (const float*)d_in[11]; const float* bd2 = (const float*)d_in[12];
    const float* Wd3  = (const float*)d_in[13]; const float* bd3 = (const float*)d_in[14];
    const float* Wd4  = (const float*)d_in[15]; const float* bd4 = (const float*)d_in[16];
    const float* protos = (const float*)d_in[17];
    const float* pw   = (const float*)d_in[18];

    float* out = (float*)d_out;
    float* recon_img   = out;               // (256,3,64,64)
    float* recon_proto = out + 3145728;     // (256,3,64,64)
    float* dists       = out + 6291456;     // (256,4,64)
    float* latent      = out + 6356992;     // (256,256,4,4) fp32 NCHW
    float* out_protos  = out + 7405568;     // (4,64,4096)
    float* mixed       = out + 8454144;     // (256,4096)

    ushort* wsu  = (ushort*)d_ws;
    ushort* bufAh = wsu;                    // 33,554,432 each plane
    ushort* bufAl = bufAh + 33554432;
    ushort* bufBh = bufAl + 33554432;       //  8,388,608
    ushort* bufBl = bufBh + 8388608;
    ushort* bufCh = bufBl + 8388608;        //  2,097,152
    ushort* bufCl = bufCh + 2097152;
    ushort* bufLh = bufCl + 2097152;        //  1,048,576
    ushort* bufLl = bufLh + 1048576;
    ushort* bufMh = bufLl + 1048576;        //  1,048,576
    ushort* bufMl = bufMh + 1048576;
    ushort* wc2h = bufMl + 1048576;         //    147,456 each
    ushort* wc2l = wc2h + 147456;
    ushort* wc3h = wc2l + 147456;
    ushort* wc3l = wc3h + 147456;
    ushort* wc4h = wc3l + 147456;           //    294,912 each
    ushort* wc4l = wc4h + 294912;
    ushort* wd1h = wc4l + 294912;           //    294,912 each
    ushort* wd1l = wd1h + 294912;
    ushort* wd2h = wd1l + 294912;           //    147,456 each
    ushort* wd2l = wd2h + 147456;
    ushort* wd3h = wd2l + 147456;
    ushort* wd3l = wd3h + 147456;
    float* pnorm = (float*)(wd3l + 147456); //        256
    float* znorm = pnorm + 256;             //        256
    float* dotpart = znorm + 256;           //    524,288

    // weight repack+split (d_ws re-poisoned every call -> redo every call)
    repack_kernel<<<576, 256, 0, stream>>>(We2, wc2h, wc2l, 128, 128);
    repack_kernel<<<576, 256, 0, stream>>>(We3, wc3h, wc3l, 128, 128);
    repack_kernel<<<1152, 256, 0, stream>>>(We4, wc4h, wc4l, 256, 128);
    repack_kernel<<<1152, 256, 0, stream>>>(Wd1, wd1h, wd1l, 128, 256);
    repack_kernel<<<576, 256, 0, stream>>>(Wd2, wd2h, wd2l, 128, 128);
    repack_kernel<<<576, 256, 0, stream>>>(Wd3, wd3h, wd3l, 128, 128);
    pnorm_kernel<<<256, 64, 0, stream>>>(protos, pnorm);

    // encoder
    conv1_kernel<<<dim3(256, 4), 256, 0, stream>>>(x, We1, be1, bufAh, bufAl);
    conv_mfma<false, 128><<<dim3(512, 1), 256, 0, stream>>>(
        bufAh, bufAl, wc2h, wc2l, be2, bufBh, bufBl, nullptr,
        128, 32, 32, 128, 16, 16, 4, 8, 0);
    conv_mfma<false, 64><<<dim3(128, 2), 256, 0, stream>>>(
        bufBh, bufBl, wc3h, wc3l, be3, bufCh, bufCl, nullptr,
        128, 16, 16, 128, 8, 8, 3, 6, 0);
    conv_mfma<false, 64><<<dim3(32, 4), 256, 0, stream>>>(
        bufCh, bufCl, wc4h, wc4l, be4, bufLh, bufLl, latent,
        128, 8, 8, 256, 4, 4, 2, 4, 1);

    // prototype block (fp32)
    pnorm_kernel<<<256, 64, 0, stream>>>(latent, znorm);
    dists_part_kernel<<<dim3(64, 8), 256, 0, stream>>>(latent, protos, dotpart);
    dists_final_kernel<<<256, 256, 0, stream>>>(dotpart, znorm, pnorm, dists);
    softmix_kernel<<<dim3(64, 16), 256, 0, stream>>>(dists, protos, pw, mixed,
                                                     bufMh, bufMl);
    hipMemcpyAsync(out_protos, protos, 1048576 * sizeof(float),
                   hipMemcpyDeviceToDevice, stream);

    // two decoders (share scratch; stream order serializes)
    for (int pass = 0; pass < 2; pass++) {
        const ushort* sh = (pass == 0) ? bufMh : bufLh;
        const ushort* sl = (pass == 0) ? bufMl : bufLl;
        float* dst = (pass == 0) ? recon_proto : recon_img;
        conv_mfma<true, 64><<<dim3(32, 2, 4), 256, 0, stream>>>(
            sh, sl, wd1h, wd1l, bd1, bufCh, bufCl, nullptr,
            256, 4, 4, 128, 8, 8, 2, 4, 0);
        conv_mfma<true, 128><<<dim3(128, 1, 4), 256, 0, stream>>>(
            bufCh, bufCl, wd2h, wd2l, bd2, bufBh, bufBl, nullptr,
            128, 8, 8, 128, 16, 16, 3, 6, 0);
        conv_mfma<true, 128><<<dim3(512, 1, 4), 256, 0, stream>>>(
            bufBh, bufBl, wd3h, wd3l, bd3, bufAh, bufAl, nullptr,
            128, 16, 16, 128, 32, 32, 4, 8, 0);
        dconv4_kernel<<<dim3(16, 256), 256, 0, stream>>>(bufAh, bufAl, Wd4, bd4, dst);
    }
}